// Round 1
// baseline (678.828 us; speedup 1.0000x reference)
//
#include <hip/hip_runtime.h>
#include <stdint.h>

#define NN 10000
#define EE 320000
#define HH1 256
#define HH2 128

typedef __attribute__((ext_vector_type(8))) short short8;
typedef __attribute__((ext_vector_type(4))) float f32x4;

static __device__ __forceinline__ short f2bf(float f) {
  union { float f; unsigned u; } v; v.f = f;
  unsigned r = (v.u + 0x7fffu + ((v.u >> 16) & 1u)) >> 16;
  return (short)r;
}

// ---------------- graph prep ----------------
__global__ void k_count(const int* __restrict__ dst, int* __restrict__ degi) {
  int e = blockIdx.x * 256 + threadIdx.x;
  if (e < EE) atomicAdd(&degi[dst[e]], 1);
}

__global__ __launch_bounds__(1024) void k_scan(const int* __restrict__ degi,
    int* __restrict__ rowst, int* __restrict__ cursor, float* __restrict__ invd) {
  __shared__ int part[1024];
  const int t = threadIdx.x;
  const int chunk = (NN + 1023) / 1024;
  int b = t * chunk, e = b + chunk;
  if (e > NN) e = NN;
  int s = 0;
  for (int i = b; i < e; ++i) s += degi[i];
  part[t] = s;
  __syncthreads();
  for (int off = 1; off < 1024; off <<= 1) {
    int v = (t >= off) ? part[t - off] : 0;
    __syncthreads();
    part[t] += v;
    __syncthreads();
  }
  int base = (t == 0) ? 0 : part[t - 1];
  for (int i = b; i < e; ++i) {
    rowst[i] = base;
    cursor[i] = base;
    invd[i] = 1.0f / (float)(degi[i] + 1);
    base += degi[i];
  }
  if (t == 1023) rowst[NN] = part[1023];
}

__global__ void k_fill(const int* __restrict__ src, const int* __restrict__ dst,
    const float* __restrict__ ew, int* __restrict__ cursor,
    int* __restrict__ csrc, float* __restrict__ cw) {
  int e = blockIdx.x * 256 + threadIdx.x;
  if (e < EE) {
    int p = atomicAdd(&cursor[dst[e]], 1);
    csrc[p] = src[e];
    cw[p] = ew[e];
  }
}

// ---------------- W1 -> bf16 ----------------
__global__ void k_w1bf(const float* __restrict__ W1, short* __restrict__ w1b) {
  long i = (long)(blockIdx.x * 256 + threadIdx.x) * 8;
  float4 a = *(const float4*)(W1 + i);
  float4 b = *(const float4*)(W1 + i + 4);
  short8 o;
  o[0] = f2bf(a.x); o[1] = f2bf(a.y); o[2] = f2bf(a.z); o[3] = f2bf(a.w);
  o[4] = f2bf(b.x); o[5] = f2bf(b.y); o[6] = f2bf(b.z); o[7] = f2bf(b.w);
  *(short8*)(w1b + i) = o;
}

// ---------------- GEMM1: ht1 = feat @ W1^T  (bf16 MFMA, fused f32->bf16) ----
// tile 64x64, BK=64, 4 waves (2x2), wave tile 32x32
__global__ __launch_bounds__(256) void k_gemm1(const float* __restrict__ feat,
    const short* __restrict__ w1b, float* __restrict__ ht1) {
  __shared__ short As[64 * 64];
  __shared__ short Bs[64 * 64];
  const int bm = (int)blockIdx.x >> 2;
  const int bn = (int)blockIdx.x & 3;
  const int t = threadIdx.x;
  const int lane = t & 63;
  const int wid = t >> 6;
  const int wm = wid >> 1, wn = wid & 1;
  const int l15 = lane & 15, l4 = lane >> 4;
  // staging: LDS row r = it*32 + (t>>3), storage slot = t&7 (lane-contiguous write)
  const int sr = t >> 3;
  const int ss = t & 7;
  const int kperm = (ss ^ (sr & 7)) * 8;  // pre-swizzled source k-offset
  const long arow0 = (long)min(bm * 64 + sr, NN - 1) * NN;
  const long arow1 = (long)min(bm * 64 + 32 + sr, NN - 1) * NN;
  const long brow0 = (long)(bn * 64 + sr) * NN;
  const long brow1 = (long)(bn * 64 + 32 + sr) * NN;
  short* adst0 = (short*)As + t * 8;
  short* adst1 = (short*)As + 2048 + t * 8;
  short* bdst0 = (short*)Bs + t * 8;
  short* bdst1 = (short*)Bs + 2048 + t * 8;

  f32x4 acc[2][2];
  const f32x4 zz = {0.f, 0.f, 0.f, 0.f};
  acc[0][0] = zz; acc[0][1] = zz; acc[1][0] = zz; acc[1][1] = zz;
  const short8 z8 = {0, 0, 0, 0, 0, 0, 0, 0};

  short8 a0, a1, b0, b1;
  {
    const float4* p0 = (const float4*)(feat + arow0 + kperm);
    const float4* p1 = (const float4*)(feat + arow1 + kperm);
    float4 f0 = p0[0], f1 = p0[1], f2 = p1[0], f3 = p1[1];
    a0[0] = f2bf(f0.x); a0[1] = f2bf(f0.y); a0[2] = f2bf(f0.z); a0[3] = f2bf(f0.w);
    a0[4] = f2bf(f1.x); a0[5] = f2bf(f1.y); a0[6] = f2bf(f1.z); a0[7] = f2bf(f1.w);
    a1[0] = f2bf(f2.x); a1[1] = f2bf(f2.y); a1[2] = f2bf(f2.z); a1[3] = f2bf(f2.w);
    a1[4] = f2bf(f3.x); a1[5] = f2bf(f3.y); a1[6] = f2bf(f3.z); a1[7] = f2bf(f3.w);
    b0 = *(const short8*)(w1b + brow0 + kperm);
    b1 = *(const short8*)(w1b + brow1 + kperm);
  }

  for (int k0 = 0; k0 < NN; k0 += 64) {
    __syncthreads();
    *(short8*)adst0 = a0;
    *(short8*)adst1 = a1;
    *(short8*)bdst0 = b0;
    *(short8*)bdst1 = b1;
    __syncthreads();
    const int kn = k0 + 64;
    if (kn < NN) {
      if (kn + kperm < NN) {
        const float4* p0 = (const float4*)(feat + arow0 + kn + kperm);
        const float4* p1 = (const float4*)(feat + arow1 + kn + kperm);
        float4 f0 = p0[0], f1 = p0[1], f2 = p1[0], f3 = p1[1];
        a0[0] = f2bf(f0.x); a0[1] = f2bf(f0.y); a0[2] = f2bf(f0.z); a0[3] = f2bf(f0.w);
        a0[4] = f2bf(f1.x); a0[5] = f2bf(f1.y); a0[6] = f2bf(f1.z); a0[7] = f2bf(f1.w);
        a1[0] = f2bf(f2.x); a1[1] = f2bf(f2.y); a1[2] = f2bf(f2.z); a1[3] = f2bf(f2.w);
        a1[4] = f2bf(f3.x); a1[5] = f2bf(f3.y); a1[6] = f2bf(f3.z); a1[7] = f2bf(f3.w);
        b0 = *(const short8*)(w1b + brow0 + kn + kperm);
        b1 = *(const short8*)(w1b + brow1 + kn + kperm);
      } else {
        a0 = z8; a1 = z8; b0 = z8; b1 = z8;
      }
    }
#pragma unroll
    for (int kk = 0; kk < 2; ++kk) {
      const int es = ((kk * 4 + l4) ^ (l15 & 7)) * 8;
      short8 af0 = *(const short8*)((short*)As + (wm * 32 + l15) * 64 + es);
      short8 af1 = *(const short8*)((short*)As + (wm * 32 + 16 + l15) * 64 + es);
      short8 bf0 = *(const short8*)((short*)Bs + (wn * 32 + l15) * 64 + es);
      short8 bf1 = *(const short8*)((short*)Bs + (wn * 32 + 16 + l15) * 64 + es);
      acc[0][0] = __builtin_amdgcn_mfma_f32_16x16x32_bf16(af0, bf0, acc[0][0], 0, 0, 0);
      acc[0][1] = __builtin_amdgcn_mfma_f32_16x16x32_bf16(af0, bf1, acc[0][1], 0, 0, 0);
      acc[1][0] = __builtin_amdgcn_mfma_f32_16x16x32_bf16(af1, bf0, acc[1][0], 0, 0, 0);
      acc[1][1] = __builtin_amdgcn_mfma_f32_16x16x32_bf16(af1, bf1, acc[1][1], 0, 0, 0);
    }
  }
#pragma unroll
  for (int mi = 0; mi < 2; ++mi) {
    const int row0 = bm * 64 + wm * 32 + mi * 16 + l4 * 4;
#pragma unroll
    for (int ni = 0; ni < 2; ++ni) {
      const int c = bn * 64 + wn * 32 + ni * 16 + l15;
#pragma unroll
      for (int r = 0; r < 4; ++r) {
        const int row = row0 + r;
        if (row < NN) ht1[(long)row * HH1 + c] = acc[mi][ni][r];
      }
    }
  }
}

// ---------------- aggregate layer 1 (+relu) ----------------
__global__ void k_agg1(const float* __restrict__ ht1, const int* __restrict__ rowst,
    const int* __restrict__ csrc, const float* __restrict__ cw,
    const float* __restrict__ invd, const float* __restrict__ b1,
    float* __restrict__ h) {
  const int node = blockIdx.x;
  const int j = threadIdx.x;
  const int s = rowst[node], e = rowst[node + 1];
  float acc = 0.f;
  for (int p = s; p < e; ++p)
    acc = fmaf(cw[p], ht1[(long)csrc[p] * HH1 + j], acc);
  float v = (acc + ht1[(long)node * HH1 + j]) * invd[node] + b1[j];
  h[(long)node * HH1 + j] = fmaxf(v, 0.f);
}

// ---------------- GEMM2: ht2 = h @ W2^T (f32 VALU) ----------------
__global__ __launch_bounds__(512) void k_gemm2(const float* __restrict__ h,
    const float* __restrict__ W2, float* __restrict__ ht2) {
  const int t = threadIdx.x;
  const int col = t & 127, rg = t >> 7;  // rg 0..3
  const long row0 = (long)blockIdx.x * 16 + rg * 4;
  const float* hp = h + row0 * HH1;
  const float* wp = W2 + col * HH1;
  float acc0 = 0.f, acc1 = 0.f, acc2 = 0.f, acc3 = 0.f;
  for (int k = 0; k < HH1; k += 4) {
    float4 wv = *(const float4*)(wp + k);
    float4 h0 = *(const float4*)(hp + k);
    float4 h1 = *(const float4*)(hp + HH1 + k);
    float4 h2 = *(const float4*)(hp + 2 * HH1 + k);
    float4 h3 = *(const float4*)(hp + 3 * HH1 + k);
    acc0 += h0.x * wv.x + h0.y * wv.y + h0.z * wv.z + h0.w * wv.w;
    acc1 += h1.x * wv.x + h1.y * wv.y + h1.z * wv.z + h1.w * wv.w;
    acc2 += h2.x * wv.x + h2.y * wv.y + h2.z * wv.z + h2.w * wv.w;
    acc3 += h3.x * wv.x + h3.y * wv.y + h3.z * wv.z + h3.w * wv.w;
  }
  ht2[row0 * HH2 + col] = acc0;
  ht2[(row0 + 1) * HH2 + col] = acc1;
  ht2[(row0 + 2) * HH2 + col] = acc2;
  ht2[(row0 + 3) * HH2 + col] = acc3;
}

// ---------------- aggregate layer 2 -> z (f32 out) + pre-swizzled bf16 ------
__global__ void k_agg2(const float* __restrict__ ht2, const int* __restrict__ rowst,
    const int* __restrict__ csrc, const float* __restrict__ cw,
    const float* __restrict__ invd, const float* __restrict__ b2,
    float* __restrict__ zout, short* __restrict__ zb) {
  const int node = blockIdx.x;
  const int j = threadIdx.x;
  const int s = rowst[node], e = rowst[node + 1];
  float acc = 0.f;
  for (int p = s; p < e; ++p)
    acc = fmaf(cw[p], ht2[(long)csrc[p] * HH2 + j], acc);
  float v = (acc + ht2[(long)node * HH2 + j]) * invd[node] + b2[j];
  zout[(long)node * HH2 + j] = v;
  const int slot = j >> 3, pos = j & 7;
  zb[node * HH2 + ((slot ^ (node & 15)) << 3) + pos] = f2bf(v);
}

// ---------------- adj = z @ z^T (bf16 MFMA, K=128, tile 128x128) ------------
__global__ __launch_bounds__(256) void k_adj(const short* __restrict__ zb,
                                             float* __restrict__ adj) {
  __shared__ short As[128 * 128];
  __shared__ short Bs[128 * 128];
  const int bmi = blockIdx.y, bni = blockIdx.x;
  const int t = threadIdx.x;
  const int lane = t & 63;
  const int wid = t >> 6;
  const int wm = wid >> 1, wn = wid & 1;
  const int l15 = lane & 15, l4 = lane >> 4;
  const int sr = t >> 4;   // 0..15
  const int ss = t & 15;
#pragma unroll
  for (int it = 0; it < 8; ++it) {
    const int r = it * 16 + sr;
    const long ga = (long)min(bmi * 128 + r, NN - 1) * HH2;
    const long gb = (long)min(bni * 128 + r, NN - 1) * HH2;
    *(short8*)((short*)As + r * 128 + ss * 8) = *(const short8*)(zb + ga + ss * 8);
    *(short8*)((short*)Bs + r * 128 + ss * 8) = *(const short8*)(zb + gb + ss * 8);
  }
  __syncthreads();
  f32x4 acc[4][4];
  const f32x4 zz = {0.f, 0.f, 0.f, 0.f};
#pragma unroll
  for (int mi = 0; mi < 4; ++mi)
#pragma unroll
    for (int ni = 0; ni < 4; ++ni) acc[mi][ni] = zz;
#pragma unroll
  for (int k4 = 0; k4 < 4; ++k4) {
    const int es = ((k4 * 4 + l4) ^ l15) * 8;
    short8 af[4], bf[4];
#pragma unroll
    for (int mi = 0; mi < 4; ++mi)
      af[mi] = *(const short8*)((short*)As + (wm * 64 + mi * 16 + l15) * 128 + es);
#pragma unroll
    for (int ni = 0; ni < 4; ++ni)
      bf[ni] = *(const short8*)((short*)Bs + (wn * 64 + ni * 16 + l15) * 128 + es);
#pragma unroll
    for (int mi = 0; mi < 4; ++mi)
#pragma unroll
      for (int ni = 0; ni < 4; ++ni)
        acc[mi][ni] = __builtin_amdgcn_mfma_f32_16x16x32_bf16(af[mi], bf[ni], acc[mi][ni], 0, 0, 0);
  }
#pragma unroll
  for (int mi = 0; mi < 4; ++mi) {
    const int row0 = bmi * 128 + wm * 64 + mi * 16 + l4 * 4;
#pragma unroll
    for (int ni = 0; ni < 4; ++ni) {
      const int c = bni * 128 + wn * 64 + ni * 16 + l15;
      if (c < NN) {
#pragma unroll
        for (int r = 0; r < 4; ++r) {
          const int row = row0 + r;
          if (row < NN) adj[(long)row * NN + c] = acc[mi][ni][r];
        }
      }
    }
  }
}

// ---------------- launch ----------------
extern "C" void kernel_launch(void* const* d_in, const int* in_sizes, int n_in,
                              void* d_out, int out_size, void* d_ws, size_t ws_size,
                              hipStream_t stream) {
  (void)in_sizes; (void)n_in; (void)out_size; (void)ws_size;
  const float* feat = (const float*)d_in[0];
  const float* W1   = (const float*)d_in[1];
  const float* b1   = (const float*)d_in[2];
  const float* W2   = (const float*)d_in[3];
  const float* b2   = (const float*)d_in[4];
  const float* ew   = (const float*)d_in[5];
  const int*   srcv = (const int*)d_in[6];
  const int*   dstv = (const int*)d_in[7];

  float* zout = (float*)d_out;
  float* adj  = zout + (long)NN * HH2;

  // workspace layout
  float* ht1  = (float*)d_ws;                 // NN*HH1 f32 (reused as ht2 later)
  float* hbuf = ht1 + (long)NN * HH1;         // NN*HH1 f32
  short* w1b  = (short*)(hbuf + (long)NN * HH1); // NN*HH1 bf16
  short* zb   = w1b + (long)NN * HH1;         // NN*HH2 bf16 (pre-swizzled)
  int*   degi = (int*)(zb + (long)NN * HH2);  // NN
  int*   rowst = degi + NN;                   // NN+1 (pad 16)
  int*   cursor = rowst + NN + 16;            // NN
  int*   csrc = cursor + NN;                  // EE
  float* cw   = (float*)(csrc + EE);          // EE
  float* invd = cw + EE;                      // NN
  float* ht2  = ht1;                          // alias (ht1 dead after k_agg1)

  hipMemsetAsync(degi, 0, NN * sizeof(int), stream);
  k_count<<<(EE + 255) / 256, 256, 0, stream>>>(dstv, degi);
  k_scan<<<1, 1024, 0, stream>>>(degi, rowst, cursor, invd);
  k_fill<<<(EE + 255) / 256, 256, 0, stream>>>(srcv, dstv, ew, cursor, csrc, cw);
  k_w1bf<<<1250, 256, 0, stream>>>(W1, w1b);
  k_gemm1<<<157 * 4, 256, 0, stream>>>(feat, w1b, ht1);
  k_agg1<<<NN, 256, 0, stream>>>(ht1, rowst, csrc, cw, invd, b1, hbuf);
  k_gemm2<<<625, 512, 0, stream>>>(hbuf, W2, ht2);
  k_agg2<<<NN, 128, 0, stream>>>(ht2, rowst, csrc, cw, invd, b2, zout, zb);
  k_adj<<<dim3(79, 79), 256, 0, stream>>>(zb, adj);
}

// Round 2
// 630.417 us; speedup vs baseline: 1.0768x; 1.0768x over previous
//
#include <hip/hip_runtime.h>
#include <stdint.h>

#define NN 10000
#define EE 320000
#define HH1 256
#define HH2 128

typedef __attribute__((ext_vector_type(8))) short short8;
typedef __attribute__((ext_vector_type(4))) float f32x4;

static __device__ __forceinline__ short f2bf(float f) {
  union { float f; unsigned u; } v; v.f = f;
  unsigned r = (v.u + 0x7fffu + ((v.u >> 16) & 1u)) >> 16;
  return (short)r;
}

// ---------------- graph prep ----------------
__global__ void k_count(const int* __restrict__ dst, int* __restrict__ degi) {
  int e = blockIdx.x * 256 + threadIdx.x;
  if (e < EE) atomicAdd(&degi[dst[e]], 1);
}

__global__ __launch_bounds__(1024) void k_scan(const int* __restrict__ degi,
    int* __restrict__ rowst, int* __restrict__ cursor, float* __restrict__ invd) {
  __shared__ int part[1024];
  const int t = threadIdx.x;
  const int chunk = (NN + 1023) / 1024;
  int b = t * chunk, e = b + chunk;
  if (e > NN) e = NN;
  int s = 0;
  for (int i = b; i < e; ++i) s += degi[i];
  part[t] = s;
  __syncthreads();
  for (int off = 1; off < 1024; off <<= 1) {
    int v = (t >= off) ? part[t - off] : 0;
    __syncthreads();
    part[t] += v;
    __syncthreads();
  }
  int base = (t == 0) ? 0 : part[t - 1];
  for (int i = b; i < e; ++i) {
    rowst[i] = base;
    cursor[i] = base;
    invd[i] = 1.0f / (float)(degi[i] + 1);
    base += degi[i];
  }
  if (t == 1023) rowst[NN] = part[1023];
}

__global__ void k_fill(const int* __restrict__ src, const int* __restrict__ dst,
    const float* __restrict__ ew, int* __restrict__ cursor,
    int* __restrict__ csrc, float* __restrict__ cw) {
  int e = blockIdx.x * 256 + threadIdx.x;
  if (e < EE) {
    int p = atomicAdd(&cursor[dst[e]], 1);
    csrc[p] = src[e];
    cw[p] = ew[e];
  }
}

// ---------------- W1 -> bf16 ----------------
__global__ void k_w1bf(const float* __restrict__ W1, short* __restrict__ w1b) {
  long i = (long)(blockIdx.x * 256 + threadIdx.x) * 8;
  float4 a = *(const float4*)(W1 + i);
  float4 b = *(const float4*)(W1 + i + 4);
  short8 o;
  o[0] = f2bf(a.x); o[1] = f2bf(a.y); o[2] = f2bf(a.z); o[3] = f2bf(a.w);
  o[4] = f2bf(b.x); o[5] = f2bf(b.y); o[6] = f2bf(b.z); o[7] = f2bf(b.w);
  *(short8*)(w1b + i) = o;
}

// ---------------- GEMM1: ht1 = feat @ W1^T  (bf16 MFMA, fused f32->bf16) ----
// tile 64x64, BK=64, 4 waves (2x2), wave tile 32x32.
// XCD-aware mapping: the 4 bn-blocks of one bm land on the SAME XCD,
// temporally adjacent -> feat row-layer fetched from HBM once, 3 L2 hits.
// Double-buffered LDS, ONE barrier per k-step; next-tile loads hide under
// the full step (cvt+ds_write+barrier+MFMA) instead of ~200cyc.
__global__ __launch_bounds__(256) void k_gemm1(const float* __restrict__ feat,
    const short* __restrict__ w1b, float* __restrict__ ht1) {
  __shared__ short As[2][64 * 64];
  __shared__ short Bs[2][64 * 64];
  const int g = (int)blockIdx.x & 7;
  const int c = (int)blockIdx.x >> 3;
  const int bn = c & 3;
  const int bm = g + ((c >> 2) << 3);
  if (bm * 64 >= NN) return;   // uniform early-exit (pad blocks)
  const int t = threadIdx.x;
  const int lane = t & 63;
  const int wid = t >> 6;
  const int wm = wid >> 1, wn = wid & 1;
  const int l15 = lane & 15, l4 = lane >> 4;
  // staging: LDS row = t>>3 (+32), slot = t&7; pre-swizzled source k-offset
  const int sr = t >> 3;
  const int ss = t & 7;
  const int kperm = (ss ^ (sr & 7)) * 8;
  const long arow0 = (long)min(bm * 64 + sr, NN - 1) * NN;
  const long arow1 = (long)min(bm * 64 + 32 + sr, NN - 1) * NN;
  const long brow0 = (long)(bn * 64 + sr) * NN;
  const long brow1 = (long)(bn * 64 + 32 + sr) * NN;

  f32x4 acc[2][2];
  const f32x4 zz = {0.f, 0.f, 0.f, 0.f};
  acc[0][0] = zz; acc[0][1] = zz; acc[1][0] = zz; acc[1][1] = zz;
  const short8 z8 = {0, 0, 0, 0, 0, 0, 0, 0};
  const float4 zf = {0.f, 0.f, 0.f, 0.f};

  float4 f0, f1, g2, g3;
  short8 b0, b1;
  {
    const float4* p0 = (const float4*)(feat + arow0 + kperm);
    const float4* p1 = (const float4*)(feat + arow1 + kperm);
    f0 = p0[0]; f1 = p0[1]; g2 = p1[0]; g3 = p1[1];
    b0 = *(const short8*)(w1b + brow0 + kperm);
    b1 = *(const short8*)(w1b + brow1 + kperm);
  }

  int p = 0;
  for (int k0 = 0; k0 < NN; k0 += 64) {
    // convert + write stage into buf[p]
    short8 a0, a1;
    a0[0] = f2bf(f0.x); a0[1] = f2bf(f0.y); a0[2] = f2bf(f0.z); a0[3] = f2bf(f0.w);
    a0[4] = f2bf(f1.x); a0[5] = f2bf(f1.y); a0[6] = f2bf(f1.z); a0[7] = f2bf(f1.w);
    a1[0] = f2bf(g2.x); a1[1] = f2bf(g2.y); a1[2] = f2bf(g2.z); a1[3] = f2bf(g2.w);
    a1[4] = f2bf(g3.x); a1[5] = f2bf(g3.y); a1[6] = f2bf(g3.z); a1[7] = f2bf(g3.w);
    *(short8*)(&As[p][0] + t * 8) = a0;
    *(short8*)(&As[p][0] + 2048 + t * 8) = a1;
    *(short8*)(&Bs[p][0] + t * 8) = b0;
    *(short8*)(&Bs[p][0] + 2048 + t * 8) = b1;
    // issue next-tile loads (consumed at next iteration's write stage)
    const int kn = k0 + 64;
    if (kn < NN) {
      if (kn + kperm + 8 <= NN) {
        const float4* p0 = (const float4*)(feat + arow0 + kn + kperm);
        const float4* p1 = (const float4*)(feat + arow1 + kn + kperm);
        f0 = p0[0]; f1 = p0[1]; g2 = p1[0]; g3 = p1[1];
        b0 = *(const short8*)(w1b + brow0 + kn + kperm);
        b1 = *(const short8*)(w1b + brow1 + kn + kperm);
      } else {
        f0 = zf; f1 = zf; g2 = zf; g3 = zf;
        b0 = z8; b1 = z8;
      }
    }
    __syncthreads();
#pragma unroll
    for (int kk = 0; kk < 2; ++kk) {
      const int es = ((kk * 4 + l4) ^ (l15 & 7)) * 8;
      short8 af0 = *(const short8*)(&As[p][0] + (wm * 32 + l15) * 64 + es);
      short8 af1 = *(const short8*)(&As[p][0] + (wm * 32 + 16 + l15) * 64 + es);
      short8 bf0 = *(const short8*)(&Bs[p][0] + (wn * 32 + l15) * 64 + es);
      short8 bf1 = *(const short8*)(&Bs[p][0] + (wn * 32 + 16 + l15) * 64 + es);
      acc[0][0] = __builtin_amdgcn_mfma_f32_16x16x32_bf16(af0, bf0, acc[0][0], 0, 0, 0);
      acc[0][1] = __builtin_amdgcn_mfma_f32_16x16x32_bf16(af0, bf1, acc[0][1], 0, 0, 0);
      acc[1][0] = __builtin_amdgcn_mfma_f32_16x16x32_bf16(af1, bf0, acc[1][0], 0, 0, 0);
      acc[1][1] = __builtin_amdgcn_mfma_f32_16x16x32_bf16(af1, bf1, acc[1][1], 0, 0, 0);
    }
    p ^= 1;
  }
#pragma unroll
  for (int mi = 0; mi < 2; ++mi) {
    const int row0 = bm * 64 + wm * 32 + mi * 16 + l4 * 4;
#pragma unroll
    for (int ni = 0; ni < 2; ++ni) {
      const int cc = bn * 64 + wn * 32 + ni * 16 + l15;
#pragma unroll
      for (int r = 0; r < 4; ++r) {
        const int row = row0 + r;
        if (row < NN) ht1[(long)row * HH1 + cc] = acc[mi][ni][r];
      }
    }
  }
}

// ---------------- aggregate layer 1 (+relu) ----------------
__global__ void k_agg1(const float* __restrict__ ht1, const int* __restrict__ rowst,
    const int* __restrict__ csrc, const float* __restrict__ cw,
    const float* __restrict__ invd, const float* __restrict__ b1,
    float* __restrict__ h) {
  const int node = blockIdx.x;
  const int j = threadIdx.x;
  const int s = rowst[node], e = rowst[node + 1];
  float acc = 0.f;
  for (int p = s; p < e; ++p)
    acc = fmaf(cw[p], ht1[(long)csrc[p] * HH1 + j], acc);
  float v = (acc + ht1[(long)node * HH1 + j]) * invd[node] + b1[j];
  h[(long)node * HH1 + j] = fmaxf(v, 0.f);
}

// ---------------- GEMM2: ht2 = h @ W2^T (f32 VALU) ----------------
__global__ __launch_bounds__(512) void k_gemm2(const float* __restrict__ h,
    const float* __restrict__ W2, float* __restrict__ ht2) {
  const int t = threadIdx.x;
  const int col = t & 127, rg = t >> 7;  // rg 0..3
  const long row0 = (long)blockIdx.x * 16 + rg * 4;
  const float* hp = h + row0 * HH1;
  const float* wp = W2 + col * HH1;
  float acc0 = 0.f, acc1 = 0.f, acc2 = 0.f, acc3 = 0.f;
  for (int k = 0; k < HH1; k += 4) {
    float4 wv = *(const float4*)(wp + k);
    float4 h0 = *(const float4*)(hp + k);
    float4 h1 = *(const float4*)(hp + HH1 + k);
    float4 h2 = *(const float4*)(hp + 2 * HH1 + k);
    float4 h3 = *(const float4*)(hp + 3 * HH1 + k);
    acc0 += h0.x * wv.x + h0.y * wv.y + h0.z * wv.z + h0.w * wv.w;
    acc1 += h1.x * wv.x + h1.y * wv.y + h1.z * wv.z + h1.w * wv.w;
    acc2 += h2.x * wv.x + h2.y * wv.y + h2.z * wv.z + h2.w * wv.w;
    acc3 += h3.x * wv.x + h3.y * wv.y + h3.z * wv.z + h3.w * wv.w;
  }
  ht2[row0 * HH2 + col] = acc0;
  ht2[(row0 + 1) * HH2 + col] = acc1;
  ht2[(row0 + 2) * HH2 + col] = acc2;
  ht2[(row0 + 3) * HH2 + col] = acc3;
}

// ---------------- aggregate layer 2 -> z (f32 out) + pre-swizzled bf16 ------
__global__ void k_agg2(const float* __restrict__ ht2, const int* __restrict__ rowst,
    const int* __restrict__ csrc, const float* __restrict__ cw,
    const float* __restrict__ invd, const float* __restrict__ b2,
    float* __restrict__ zout, short* __restrict__ zb) {
  const int node = blockIdx.x;
  const int j = threadIdx.x;
  const int s = rowst[node], e = rowst[node + 1];
  float acc = 0.f;
  for (int p = s; p < e; ++p)
    acc = fmaf(cw[p], ht2[(long)csrc[p] * HH2 + j], acc);
  float v = (acc + ht2[(long)node * HH2 + j]) * invd[node] + b2[j];
  zout[(long)node * HH2 + j] = v;
  const int slot = j >> 3, pos = j & 7;
  zb[node * HH2 + ((slot ^ (node & 15)) << 3) + pos] = f2bf(v);
}

// ---------------- adj = z @ z^T (bf16 MFMA, K=128, tile 128x128) ------------
__global__ __launch_bounds__(256) void k_adj(const short* __restrict__ zb,
                                             float* __restrict__ adj) {
  __shared__ short As[128 * 128];
  __shared__ short Bs[128 * 128];
  const int bmi = blockIdx.y, bni = blockIdx.x;
  const int t = threadIdx.x;
  const int lane = t & 63;
  const int wid = t >> 6;
  const int wm = wid >> 1, wn = wid & 1;
  const int l15 = lane & 15, l4 = lane >> 4;
  const int sr = t >> 4;   // 0..15
  const int ss = t & 15;
#pragma unroll
  for (int it = 0; it < 8; ++it) {
    const int r = it * 16 + sr;
    const long ga = (long)min(bmi * 128 + r, NN - 1) * HH2;
    const long gb = (long)min(bni * 128 + r, NN - 1) * HH2;
    *(short8*)((short*)As + r * 128 + ss * 8) = *(const short8*)(zb + ga + ss * 8);
    *(short8*)((short*)Bs + r * 128 + ss * 8) = *(const short8*)(zb + gb + ss * 8);
  }
  __syncthreads();
  f32x4 acc[4][4];
  const f32x4 zz = {0.f, 0.f, 0.f, 0.f};
#pragma unroll
  for (int mi = 0; mi < 4; ++mi)
#pragma unroll
    for (int ni = 0; ni < 4; ++ni) acc[mi][ni] = zz;
#pragma unroll
  for (int k4 = 0; k4 < 4; ++k4) {
    const int es = ((k4 * 4 + l4) ^ l15) * 8;
    short8 af[4], bf[4];
#pragma unroll
    for (int mi = 0; mi < 4; ++mi)
      af[mi] = *(const short8*)((short*)As + (wm * 64 + mi * 16 + l15) * 128 + es);
#pragma unroll
    for (int ni = 0; ni < 4; ++ni)
      bf[ni] = *(const short8*)((short*)Bs + (wn * 64 + ni * 16 + l15) * 128 + es);
#pragma unroll
    for (int mi = 0; mi < 4; ++mi)
#pragma unroll
      for (int ni = 0; ni < 4; ++ni)
        acc[mi][ni] = __builtin_amdgcn_mfma_f32_16x16x32_bf16(af[mi], bf[ni], acc[mi][ni], 0, 0, 0);
  }
#pragma unroll
  for (int mi = 0; mi < 4; ++mi) {
    const int row0 = bmi * 128 + wm * 64 + mi * 16 + l4 * 4;
#pragma unroll
    for (int ni = 0; ni < 4; ++ni) {
      const int cc = bni * 128 + wn * 64 + ni * 16 + l15;
      if (cc < NN) {
#pragma unroll
        for (int r = 0; r < 4; ++r) {
          const int row = row0 + r;
          if (row < NN) adj[(long)row * NN + cc] = acc[mi][ni][r];
        }
      }
    }
  }
}

// ---------------- launch ----------------
extern "C" void kernel_launch(void* const* d_in, const int* in_sizes, int n_in,
                              void* d_out, int out_size, void* d_ws, size_t ws_size,
                              hipStream_t stream) {
  (void)in_sizes; (void)n_in; (void)out_size; (void)ws_size;
  const float* feat = (const float*)d_in[0];
  const float* W1   = (const float*)d_in[1];
  const float* b1   = (const float*)d_in[2];
  const float* W2   = (const float*)d_in[3];
  const float* b2   = (const float*)d_in[4];
  const float* ew   = (const float*)d_in[5];
  const int*   srcv = (const int*)d_in[6];
  const int*   dstv = (const int*)d_in[7];

  float* zout = (float*)d_out;
  float* adj  = zout + (long)NN * HH2;

  // workspace layout
  float* ht1  = (float*)d_ws;                 // NN*HH1 f32 (reused as ht2 later)
  float* hbuf = ht1 + (long)NN * HH1;         // NN*HH1 f32
  short* w1b  = (short*)(hbuf + (long)NN * HH1); // NN*HH1 bf16
  short* zb   = w1b + (long)NN * HH1;         // NN*HH2 bf16 (pre-swizzled)
  int*   degi = (int*)(zb + (long)NN * HH2);  // NN
  int*   rowst = degi + NN;                   // NN+1 (pad 16)
  int*   cursor = rowst + NN + 16;            // NN
  int*   csrc = cursor + NN;                  // EE
  float* cw   = (float*)(csrc + EE);          // EE
  float* invd = cw + EE;                      // NN
  float* ht2  = ht1;                          // alias (ht1 dead after k_agg1)

  hipMemsetAsync(degi, 0, NN * sizeof(int), stream);
  k_count<<<(EE + 255) / 256, 256, 0, stream>>>(dstv, degi);
  k_scan<<<1, 1024, 0, stream>>>(degi, rowst, cursor, invd);
  k_fill<<<(EE + 255) / 256, 256, 0, stream>>>(srcv, dstv, ew, cursor, csrc, cw);
  k_w1bf<<<1250, 256, 0, stream>>>(W1, w1b);
  k_gemm1<<<640, 256, 0, stream>>>(feat, w1b, ht1);
  k_agg1<<<NN, 256, 0, stream>>>(ht1, rowst, csrc, cw, invd, b1, hbuf);
  k_gemm2<<<625, 512, 0, stream>>>(hbuf, W2, ht2);
  k_agg2<<<NN, 128, 0, stream>>>(ht2, rowst, csrc, cw, invd, b2, zout, zb);
  k_adj<<<dim3(79, 79), 256, 0, stream>>>(zb, adj);
}

// Round 3
// 599.094 us; speedup vs baseline: 1.1331x; 1.0523x over previous
//
#include <hip/hip_runtime.h>
#include <stdint.h>

#define NN 10000
#define EE 320000
#define HH1 256
#define HH2 128
#define NSPLIT 4
#define KCH 2560   // K chunk per split (ceil(10000/4) rounded to 64)

typedef __attribute__((ext_vector_type(8))) short short8;
typedef __attribute__((ext_vector_type(4))) float f32x4;

static __device__ __forceinline__ short f2bf(float f) {
  union { float f; unsigned u; } v; v.f = f;
  unsigned r = (v.u + 0x7fffu + ((v.u >> 16) & 1u)) >> 16;
  return (short)r;
}

// ---------------- graph prep ----------------
__global__ void k_count(const int* __restrict__ dst, int* __restrict__ degi) {
  int e = blockIdx.x * 256 + threadIdx.x;
  if (e < EE) atomicAdd(&degi[dst[e]], 1);
}

__global__ __launch_bounds__(1024) void k_scan(const int* __restrict__ degi,
    int* __restrict__ rowst, int* __restrict__ cursor, float* __restrict__ invd) {
  __shared__ int part[1024];
  const int t = threadIdx.x;
  const int chunk = (NN + 1023) / 1024;
  int b = t * chunk, e = b + chunk;
  if (e > NN) e = NN;
  int s = 0;
  for (int i = b; i < e; ++i) s += degi[i];
  part[t] = s;
  __syncthreads();
  for (int off = 1; off < 1024; off <<= 1) {
    int v = (t >= off) ? part[t - off] : 0;
    __syncthreads();
    part[t] += v;
    __syncthreads();
  }
  int base = (t == 0) ? 0 : part[t - 1];
  for (int i = b; i < e; ++i) {
    rowst[i] = base;
    cursor[i] = base;
    invd[i] = 1.0f / (float)(degi[i] + 1);
    base += degi[i];
  }
  if (t == 1023) rowst[NN] = part[1023];
}

__global__ void k_fill(const int* __restrict__ src, const int* __restrict__ dst,
    const float* __restrict__ ew, int* __restrict__ cursor,
    int* __restrict__ csrc, float* __restrict__ cw) {
  int e = blockIdx.x * 256 + threadIdx.x;
  if (e < EE) {
    int p = atomicAdd(&cursor[dst[e]], 1);
    csrc[p] = src[e];
    cw[p] = ew[e];
  }
}

// ---------------- W1 -> bf16 ----------------
__global__ void k_w1bf(const float* __restrict__ W1, short* __restrict__ w1b) {
  long i = (long)(blockIdx.x * 256 + threadIdx.x) * 8;
  float4 a = *(const float4*)(W1 + i);
  float4 b = *(const float4*)(W1 + i + 4);
  short8 o;
  o[0] = f2bf(a.x); o[1] = f2bf(a.y); o[2] = f2bf(a.z); o[3] = f2bf(a.w);
  o[4] = f2bf(b.x); o[5] = f2bf(b.y); o[6] = f2bf(b.z); o[7] = f2bf(b.w);
  *(short8*)(w1b + i) = o;
}

// ---------------- GEMM1: ht1 = feat @ W1^T  (bf16 MFMA, fused f32->bf16) ----
// tile 64x64, BK=64, 4 waves (2x2), wave tile 32x32.
// K-split 4: split s covers k in [s*KCH, min((s+1)*KCH, NN)), writing f32
// partials; k_red1 sums them. Grid 4*640 -> ~5 resident blocks/CU (LDS-capped)
// so the per-step latency chain is covered by ~20 waves/CU instead of 8.
// XCD-aware mapping: 4 bn-blocks of one (split,bm) share an XCD, adjacent.
__global__ __launch_bounds__(256) void k_gemm1(const float* __restrict__ feat,
    const short* __restrict__ w1b, float* __restrict__ P0, float* __restrict__ P1,
    float* __restrict__ P2, float* __restrict__ P3) {
  __shared__ short As[2][64 * 64];
  __shared__ short Bs[2][64 * 64];
  const int bid = (int)blockIdx.x;
  const int split = bid >> 9;          // /512? no: 640 per split -> use div
  // 640 blocks per split:
  const int sp = bid / 640;
  const int r = bid - sp * 640;
  const int g = r & 7;
  const int c = r >> 3;
  const int bn = c & 3;
  const int bm = g + ((c >> 2) << 3);
  (void)split;
  if (bm * 64 >= NN) return;   // uniform early-exit (pad blocks)
  const int ks = sp * KCH;
  const int ke = (ks + KCH < NN) ? ks + KCH : NN;
  float* __restrict__ outp = (sp == 0) ? P0 : (sp == 1) ? P1 : (sp == 2) ? P2 : P3;

  const int t = threadIdx.x;
  const int lane = t & 63;
  const int wid = t >> 6;
  const int wm = wid >> 1, wn = wid & 1;
  const int l15 = lane & 15, l4 = lane >> 4;
  const int sr = t >> 3;
  const int ss = t & 7;
  const int kperm = (ss ^ (sr & 7)) * 8;
  const long arow0 = (long)min(bm * 64 + sr, NN - 1) * NN;
  const long arow1 = (long)min(bm * 64 + 32 + sr, NN - 1) * NN;
  const long brow0 = (long)(bn * 64 + sr) * NN;
  const long brow1 = (long)(bn * 64 + 32 + sr) * NN;

  f32x4 acc[2][2];
  const f32x4 zz = {0.f, 0.f, 0.f, 0.f};
  acc[0][0] = zz; acc[0][1] = zz; acc[1][0] = zz; acc[1][1] = zz;
  const short8 z8 = {0, 0, 0, 0, 0, 0, 0, 0};
  const float4 zf = {0.f, 0.f, 0.f, 0.f};

  float4 f0, f1, g2, g3;
  short8 b0, b1;
  {
    // prologue load at ks: ks+kperm+8 <= 7744+8 <= NN always
    const float4* p0 = (const float4*)(feat + arow0 + ks + kperm);
    const float4* p1 = (const float4*)(feat + arow1 + ks + kperm);
    f0 = p0[0]; f1 = p0[1]; g2 = p1[0]; g3 = p1[1];
    b0 = *(const short8*)(w1b + brow0 + ks + kperm);
    b1 = *(const short8*)(w1b + brow1 + ks + kperm);
  }

  int p = 0;
  for (int k0 = ks; k0 < ke; k0 += 64) {
    short8 a0, a1;
    a0[0] = f2bf(f0.x); a0[1] = f2bf(f0.y); a0[2] = f2bf(f0.z); a0[3] = f2bf(f0.w);
    a0[4] = f2bf(f1.x); a0[5] = f2bf(f1.y); a0[6] = f2bf(f1.z); a0[7] = f2bf(f1.w);
    a1[0] = f2bf(g2.x); a1[1] = f2bf(g2.y); a1[2] = f2bf(g2.z); a1[3] = f2bf(g2.w);
    a1[4] = f2bf(g3.x); a1[5] = f2bf(g3.y); a1[6] = f2bf(g3.z); a1[7] = f2bf(g3.w);
    *(short8*)(&As[p][0] + t * 8) = a0;
    *(short8*)(&As[p][0] + 2048 + t * 8) = a1;
    *(short8*)(&Bs[p][0] + t * 8) = b0;
    *(short8*)(&Bs[p][0] + 2048 + t * 8) = b1;
    const int kn = k0 + 64;
    if (kn < ke) {
      if (kn + kperm + 8 <= ke) {
        const float4* p0 = (const float4*)(feat + arow0 + kn + kperm);
        const float4* p1 = (const float4*)(feat + arow1 + kn + kperm);
        f0 = p0[0]; f1 = p0[1]; g2 = p1[0]; g3 = p1[1];
        b0 = *(const short8*)(w1b + brow0 + kn + kperm);
        b1 = *(const short8*)(w1b + brow1 + kn + kperm);
      } else {
        f0 = zf; f1 = zf; g2 = zf; g3 = zf;
        b0 = z8; b1 = z8;
      }
    }
    __syncthreads();
#pragma unroll
    for (int kk = 0; kk < 2; ++kk) {
      const int es = ((kk * 4 + l4) ^ (l15 & 7)) * 8;
      short8 af0 = *(const short8*)(&As[p][0] + (wm * 32 + l15) * 64 + es);
      short8 af1 = *(const short8*)(&As[p][0] + (wm * 32 + 16 + l15) * 64 + es);
      short8 bf0 = *(const short8*)(&Bs[p][0] + (wn * 32 + l15) * 64 + es);
      short8 bf1 = *(const short8*)(&Bs[p][0] + (wn * 32 + 16 + l15) * 64 + es);
      acc[0][0] = __builtin_amdgcn_mfma_f32_16x16x32_bf16(af0, bf0, acc[0][0], 0, 0, 0);
      acc[0][1] = __builtin_amdgcn_mfma_f32_16x16x32_bf16(af0, bf1, acc[0][1], 0, 0, 0);
      acc[1][0] = __builtin_amdgcn_mfma_f32_16x16x32_bf16(af1, bf0, acc[1][0], 0, 0, 0);
      acc[1][1] = __builtin_amdgcn_mfma_f32_16x16x32_bf16(af1, bf1, acc[1][1], 0, 0, 0);
    }
    p ^= 1;
  }
#pragma unroll
  for (int mi = 0; mi < 2; ++mi) {
    const int row0 = bm * 64 + wm * 32 + mi * 16 + l4 * 4;
#pragma unroll
    for (int ni = 0; ni < 2; ++ni) {
      const int cc = bn * 64 + wn * 32 + ni * 16 + l15;
#pragma unroll
      for (int r2 = 0; r2 < 4; ++r2) {
        const int row = row0 + r2;
        if (row < NN) outp[(long)row * HH1 + cc] = acc[mi][ni][r2];
      }
    }
  }
}

// ---------------- reduce 4 partials -> ht1 (in place over P0) --------------
__global__ void k_red1(const float* __restrict__ P0, const float* __restrict__ P1,
    const float* __restrict__ P2, const float* __restrict__ P3,
    float* __restrict__ o) {
  const long i = (long)(blockIdx.x * 256 + threadIdx.x) * 4;
  f32x4 a = *(const f32x4*)(P0 + i);
  f32x4 b = *(const f32x4*)(P1 + i);
  f32x4 c = *(const f32x4*)(P2 + i);
  f32x4 d = *(const f32x4*)(P3 + i);
  *(f32x4*)(o + i) = (a + b) + (c + d);
}

// ---------------- aggregate layer 1 (+relu) ----------------
__global__ void k_agg1(const float* __restrict__ ht1, const int* __restrict__ rowst,
    const int* __restrict__ csrc, const float* __restrict__ cw,
    const float* __restrict__ invd, const float* __restrict__ b1,
    float* __restrict__ h) {
  const int node = blockIdx.x;
  const int j = threadIdx.x;
  const int s = rowst[node], e = rowst[node + 1];
  float acc = 0.f;
  for (int p = s; p < e; ++p)
    acc = fmaf(cw[p], ht1[(long)csrc[p] * HH1 + j], acc);
  float v = (acc + ht1[(long)node * HH1 + j]) * invd[node] + b1[j];
  h[(long)node * HH1 + j] = fmaxf(v, 0.f);
}

// ---------------- GEMM2: ht2 = h @ W2^T (f32 VALU) ----------------
__global__ __launch_bounds__(512) void k_gemm2(const float* __restrict__ h,
    const float* __restrict__ W2, float* __restrict__ ht2) {
  const int t = threadIdx.x;
  const int col = t & 127, rg = t >> 7;  // rg 0..3
  const long row0 = (long)blockIdx.x * 16 + rg * 4;
  const float* hp = h + row0 * HH1;
  const float* wp = W2 + col * HH1;
  float acc0 = 0.f, acc1 = 0.f, acc2 = 0.f, acc3 = 0.f;
  for (int k = 0; k < HH1; k += 4) {
    float4 wv = *(const float4*)(wp + k);
    float4 h0 = *(const float4*)(hp + k);
    float4 h1 = *(const float4*)(hp + HH1 + k);
    float4 h2 = *(const float4*)(hp + 2 * HH1 + k);
    float4 h3 = *(const float4*)(hp + 3 * HH1 + k);
    acc0 += h0.x * wv.x + h0.y * wv.y + h0.z * wv.z + h0.w * wv.w;
    acc1 += h1.x * wv.x + h1.y * wv.y + h1.z * wv.z + h1.w * wv.w;
    acc2 += h2.x * wv.x + h2.y * wv.y + h2.z * wv.z + h2.w * wv.w;
    acc3 += h3.x * wv.x + h3.y * wv.y + h3.z * wv.z + h3.w * wv.w;
  }
  ht2[row0 * HH2 + col] = acc0;
  ht2[(row0 + 1) * HH2 + col] = acc1;
  ht2[(row0 + 2) * HH2 + col] = acc2;
  ht2[(row0 + 3) * HH2 + col] = acc3;
}

// ---------------- aggregate layer 2 -> z (f32 out) + pre-swizzled bf16 ------
__global__ void k_agg2(const float* __restrict__ ht2, const int* __restrict__ rowst,
    const int* __restrict__ csrc, const float* __restrict__ cw,
    const float* __restrict__ invd, const float* __restrict__ b2,
    float* __restrict__ zout, short* __restrict__ zb) {
  const int node = blockIdx.x;
  const int j = threadIdx.x;
  const int s = rowst[node], e = rowst[node + 1];
  float acc = 0.f;
  for (int p = s; p < e; ++p)
    acc = fmaf(cw[p], ht2[(long)csrc[p] * HH2 + j], acc);
  float v = (acc + ht2[(long)node * HH2 + j]) * invd[node] + b2[j];
  zout[(long)node * HH2 + j] = v;
  const int slot = j >> 3, pos = j & 7;
  zb[node * HH2 + ((slot ^ (node & 15)) << 3) + pos] = f2bf(v);
}

// ---------------- adj = z @ z^T (bf16 MFMA, K=128, tile 128x128) ------------
__global__ __launch_bounds__(256) void k_adj(const short* __restrict__ zb,
                                             float* __restrict__ adj) {
  __shared__ short As[128 * 128];
  __shared__ short Bs[128 * 128];
  const int bmi = blockIdx.y, bni = blockIdx.x;
  const int t = threadIdx.x;
  const int lane = t & 63;
  const int wid = t >> 6;
  const int wm = wid >> 1, wn = wid & 1;
  const int l15 = lane & 15, l4 = lane >> 4;
  const int sr = t >> 4;   // 0..15
  const int ss = t & 15;
#pragma unroll
  for (int it = 0; it < 8; ++it) {
    const int r = it * 16 + sr;
    const long ga = (long)min(bmi * 128 + r, NN - 1) * HH2;
    const long gb = (long)min(bni * 128 + r, NN - 1) * HH2;
    *(short8*)((short*)As + r * 128 + ss * 8) = *(const short8*)(zb + ga + ss * 8);
    *(short8*)((short*)Bs + r * 128 + ss * 8) = *(const short8*)(zb + gb + ss * 8);
  }
  __syncthreads();
  f32x4 acc[4][4];
  const f32x4 zz = {0.f, 0.f, 0.f, 0.f};
#pragma unroll
  for (int mi = 0; mi < 4; ++mi)
#pragma unroll
    for (int ni = 0; ni < 4; ++ni) acc[mi][ni] = zz;
#pragma unroll
  for (int k4 = 0; k4 < 4; ++k4) {
    const int es = ((k4 * 4 + l4) ^ l15) * 8;
    short8 af[4], bf[4];
#pragma unroll
    for (int mi = 0; mi < 4; ++mi)
      af[mi] = *(const short8*)((short*)As + (wm * 64 + mi * 16 + l15) * 128 + es);
#pragma unroll
    for (int ni = 0; ni < 4; ++ni)
      bf[ni] = *(const short8*)((short*)Bs + (wn * 64 + ni * 16 + l15) * 128 + es);
#pragma unroll
    for (int mi = 0; mi < 4; ++mi)
#pragma unroll
      for (int ni = 0; ni < 4; ++ni)
        acc[mi][ni] = __builtin_amdgcn_mfma_f32_16x16x32_bf16(af[mi], bf[ni], acc[mi][ni], 0, 0, 0);
  }
#pragma unroll
  for (int mi = 0; mi < 4; ++mi) {
    const int row0 = bmi * 128 + wm * 64 + mi * 16 + l4 * 4;
#pragma unroll
    for (int ni = 0; ni < 4; ++ni) {
      const int cc = bni * 128 + wn * 64 + ni * 16 + l15;
      if (cc < NN) {
#pragma unroll
        for (int r = 0; r < 4; ++r) {
          const int row = row0 + r;
          if (row < NN) adj[(long)row * NN + cc] = acc[mi][ni][r];
        }
      }
    }
  }
}

// ---------------- launch ----------------
extern "C" void kernel_launch(void* const* d_in, const int* in_sizes, int n_in,
                              void* d_out, int out_size, void* d_ws, size_t ws_size,
                              hipStream_t stream) {
  (void)in_sizes; (void)n_in; (void)out_size; (void)ws_size;
  const float* feat = (const float*)d_in[0];
  const float* W1   = (const float*)d_in[1];
  const float* b1   = (const float*)d_in[2];
  const float* W2   = (const float*)d_in[3];
  const float* b2   = (const float*)d_in[4];
  const float* ew   = (const float*)d_in[5];
  const int*   srcv = (const int*)d_in[6];
  const int*   dstv = (const int*)d_in[7];

  float* zout = (float*)d_out;
  float* adj  = zout + (long)NN * HH2;

  // workspace layout
  float* ht1  = (float*)d_ws;                 // NN*HH1 f32 = partial 0; later ht2
  float* hbuf = ht1 + (long)NN * HH1;         // NN*HH1 f32 = partial 1; later h
  short* w1b  = (short*)(hbuf + (long)NN * HH1); // NN*HH1 bf16
  short* zb   = w1b + (long)NN * HH1;         // NN*HH2 bf16 (pre-swizzled)
  int*   degi = (int*)(zb + (long)NN * HH2);  // NN
  int*   rowst = degi + NN;                   // NN+1 (pad 16)
  int*   cursor = rowst + NN + 16;            // NN
  int*   csrc = cursor + NN;                  // EE
  float* cw   = (float*)(csrc + EE);          // EE
  float* invd = cw + EE;                      // NN
  float* P2   = invd + NN + 16;               // NN*HH1 f32 = partial 2
  float* P3   = P2 + (long)NN * HH1;          // NN*HH1 f32 = partial 3
  float* ht2  = ht1;                          // alias (ht1 dead after k_agg1)

  hipMemsetAsync(degi, 0, NN * sizeof(int), stream);
  k_count<<<(EE + 255) / 256, 256, 0, stream>>>(dstv, degi);
  k_scan<<<1, 1024, 0, stream>>>(degi, rowst, cursor, invd);
  k_fill<<<(EE + 255) / 256, 256, 0, stream>>>(srcv, dstv, ew, cursor, csrc, cw);
  k_w1bf<<<1250, 256, 0, stream>>>(W1, w1b);
  k_gemm1<<<640 * NSPLIT, 256, 0, stream>>>(feat, w1b, ht1, hbuf, P2, P3);
  k_red1<<<2500, 256, 0, stream>>>(ht1, hbuf, P2, P3, ht1);
  k_agg1<<<NN, 256, 0, stream>>>(ht1, rowst, csrc, cw, invd, b1, hbuf);
  k_gemm2<<<625, 512, 0, stream>>>(hbuf, W2, ht2);
  k_agg2<<<NN, 128, 0, stream>>>(ht2, rowst, csrc, cw, invd, b2, zout, zb);
  k_adj<<<dim3(79, 79), 256, 0, stream>>>(zb, adj);
}

// Round 4
// 576.920 us; speedup vs baseline: 1.1766x; 1.0384x over previous
//
#include <hip/hip_runtime.h>
#include <stdint.h>

#define NN 10000
#define EE 320000
#define HH1 256
#define HH2 128
#define NSPLIT 4
#define KCH 2560   // K chunk per split

typedef __attribute__((ext_vector_type(8))) short short8;
typedef __attribute__((ext_vector_type(4))) float f32x4;

// RNE f32->bf16 via native cast: compiles to v_cvt_pk_bf16_f32 on gfx950
// (hand-rolled bit-twiddle is ~4 VALU/elem and never fuses).
static __device__ __forceinline__ short f2bf(float f) {
  union { __bf16 h; short s; } u;
  u.h = (__bf16)f;
  return u.s;
}

// ---------------- graph prep ----------------
__global__ void k_count(const int* __restrict__ dst, int* __restrict__ degi) {
  int e = blockIdx.x * 256 + threadIdx.x;
  if (e < EE) atomicAdd(&degi[dst[e]], 1);
}

__global__ __launch_bounds__(1024) void k_scan(const int* __restrict__ degi,
    int* __restrict__ rowst, int* __restrict__ cursor, float* __restrict__ invd) {
  __shared__ int part[1024];
  const int t = threadIdx.x;
  const int chunk = (NN + 1023) / 1024;
  int b = t * chunk, e = b + chunk;
  if (e > NN) e = NN;
  int s = 0;
  for (int i = b; i < e; ++i) s += degi[i];
  part[t] = s;
  __syncthreads();
  for (int off = 1; off < 1024; off <<= 1) {
    int v = (t >= off) ? part[t - off] : 0;
    __syncthreads();
    part[t] += v;
    __syncthreads();
  }
  int base = (t == 0) ? 0 : part[t - 1];
  for (int i = b; i < e; ++i) {
    rowst[i] = base;
    cursor[i] = base;
    invd[i] = 1.0f / (float)(degi[i] + 1);
    base += degi[i];
  }
  if (t == 1023) rowst[NN] = part[1023];
}

__global__ void k_fill(const int* __restrict__ src, const int* __restrict__ dst,
    const float* __restrict__ ew, int* __restrict__ cursor,
    int* __restrict__ csrc, float* __restrict__ cw) {
  int e = blockIdx.x * 256 + threadIdx.x;
  if (e < EE) {
    int p = atomicAdd(&cursor[dst[e]], 1);
    csrc[p] = src[e];
    cw[p] = ew[e];
  }
}

// ---------------- W1 -> bf16 ----------------
__global__ void k_w1bf(const float* __restrict__ W1, short* __restrict__ w1b) {
  long i = (long)(blockIdx.x * 256 + threadIdx.x) * 8;
  float4 a = *(const float4*)(W1 + i);
  float4 b = *(const float4*)(W1 + i + 4);
  short8 o;
  o[0] = f2bf(a.x); o[1] = f2bf(a.y); o[2] = f2bf(a.z); o[3] = f2bf(a.w);
  o[4] = f2bf(b.x); o[5] = f2bf(b.y); o[6] = f2bf(b.z); o[7] = f2bf(b.w);
  *(short8*)(w1b + i) = o;
}

// ---------------- GEMM1: ht1 = feat @ W1^T  (bf16 MFMA, fused f32->bf16) ----
// tile 64x64, BK=64, 4 waves (2x2), K-split 4 into f32 partials.
// Depth-2 register prefetch: loads for chunk c+2 issued while staging chunk c,
// so the load->use gap spans two full chunk bodies (~HBM latency).
// One barrier per chunk; LDS double-buffered.
__global__ __launch_bounds__(256) void k_gemm1(const float* __restrict__ feat,
    const short* __restrict__ w1b, float* __restrict__ P0, float* __restrict__ P1,
    float* __restrict__ P2, float* __restrict__ P3) {
  __shared__ short As[2][64 * 64];
  __shared__ short Bs[2][64 * 64];
  const int bid = (int)blockIdx.x;
  const int sp = bid / 640;
  const int r = bid - sp * 640;
  const int g = r & 7;
  const int c = r >> 3;
  const int bn = c & 3;
  const int bm = g + ((c >> 2) << 3);
  if (bm * 64 >= NN) return;
  const int ks = sp * KCH;
  const int ke = (ks + KCH < NN) ? ks + KCH : NN;
  float* __restrict__ outp = (sp == 0) ? P0 : (sp == 1) ? P1 : (sp == 2) ? P2 : P3;

  const int t = threadIdx.x;
  const int lane = t & 63;
  const int wid = t >> 6;
  const int wm = wid >> 1, wn = wid & 1;
  const int l15 = lane & 15, l4 = lane >> 4;
  const int sr = t >> 3;
  const int ss = t & 7;
  const int kperm = (ss ^ (sr & 7)) * 8;
  const long arow0 = (long)min(bm * 64 + sr, NN - 1) * NN;
  const long arow1 = (long)min(bm * 64 + 32 + sr, NN - 1) * NN;
  const long brow0 = (long)(bn * 64 + sr) * NN;
  const long brow1 = (long)(bn * 64 + 32 + sr) * NN;

  f32x4 acc[2][2];
  const f32x4 zz = {0.f, 0.f, 0.f, 0.f};
  acc[0][0] = zz; acc[0][1] = zz; acc[1][0] = zz; acc[1][1] = zz;
  const short8 z8 = {0, 0, 0, 0, 0, 0, 0, 0};
  const float4 zf = {0.f, 0.f, 0.f, 0.f};

  // two named prefetch register sets (static indexing — no scratch)
  float4 a00 = zf, a01 = zf, a02 = zf, a03 = zf;
  float4 a10 = zf, a11 = zf, a12 = zf, a13 = zf;
  short8 b00 = z8, b01 = z8, b10 = z8, b11 = z8;

#define LOADSET(A0, A1, A2, A3, B0, B1, KK) do {                               \
    const int _k = (KK);                                                       \
    if (_k < ke) {                                                             \
      if (_k + kperm + 8 <= ke) {                                              \
        const float4* _p0 = (const float4*)(feat + arow0 + _k + kperm);        \
        const float4* _p1 = (const float4*)(feat + arow1 + _k + kperm);        \
        A0 = _p0[0]; A1 = _p0[1]; A2 = _p1[0]; A3 = _p1[1];                    \
        B0 = *(const short8*)(w1b + brow0 + _k + kperm);                       \
        B1 = *(const short8*)(w1b + brow1 + _k + kperm);                       \
      } else {                                                                 \
        A0 = zf; A1 = zf; A2 = zf; A3 = zf; B0 = z8; B1 = z8;                  \
      }                                                                        \
    }                                                                          \
  } while (0)

#define STAGE(A0, A1, A2, A3, B0, B1) do {                                     \
    short8 _s0, _s1;                                                           \
    _s0[0] = f2bf(A0.x); _s0[1] = f2bf(A0.y); _s0[2] = f2bf(A0.z);             \
    _s0[3] = f2bf(A0.w); _s0[4] = f2bf(A1.x); _s0[5] = f2bf(A1.y);             \
    _s0[6] = f2bf(A1.z); _s0[7] = f2bf(A1.w);                                  \
    _s1[0] = f2bf(A2.x); _s1[1] = f2bf(A2.y); _s1[2] = f2bf(A2.z);             \
    _s1[3] = f2bf(A2.w); _s1[4] = f2bf(A3.x); _s1[5] = f2bf(A3.y);             \
    _s1[6] = f2bf(A3.z); _s1[7] = f2bf(A3.w);                                  \
    *(short8*)(&As[p][0] + t * 8) = _s0;                                       \
    *(short8*)(&As[p][0] + 2048 + t * 8) = _s1;                                \
    *(short8*)(&Bs[p][0] + t * 8) = B0;                                        \
    *(short8*)(&Bs[p][0] + 2048 + t * 8) = B1;                                 \
  } while (0)

#define MFMA_STEP() do {                                                       \
    _Pragma("unroll")                                                          \
    for (int kk = 0; kk < 2; ++kk) {                                           \
      const int es = ((kk * 4 + l4) ^ (l15 & 7)) * 8;                          \
      short8 af0 = *(const short8*)(&As[p][0] + (wm * 32 + l15) * 64 + es);    \
      short8 af1 = *(const short8*)(&As[p][0] + (wm * 32 + 16 + l15) * 64 + es);\
      short8 bf0 = *(const short8*)(&Bs[p][0] + (wn * 32 + l15) * 64 + es);    \
      short8 bf1 = *(const short8*)(&Bs[p][0] + (wn * 32 + 16 + l15) * 64 + es);\
      acc[0][0] = __builtin_amdgcn_mfma_f32_16x16x32_bf16(af0, bf0, acc[0][0], 0, 0, 0); \
      acc[0][1] = __builtin_amdgcn_mfma_f32_16x16x32_bf16(af0, bf1, acc[0][1], 0, 0, 0); \
      acc[1][0] = __builtin_amdgcn_mfma_f32_16x16x32_bf16(af1, bf0, acc[1][0], 0, 0, 0); \
      acc[1][1] = __builtin_amdgcn_mfma_f32_16x16x32_bf16(af1, bf1, acc[1][1], 0, 0, 0); \
    }                                                                          \
  } while (0)

  LOADSET(a00, a01, a02, a03, b00, b01, ks);
  LOADSET(a10, a11, a12, a13, b10, b11, ks + 64);

  int p = 0;
  int k0 = ks;
  while (k0 + 64 < ke) {   // at least two chunks remain
    STAGE(a00, a01, a02, a03, b00, b01);
    LOADSET(a00, a01, a02, a03, b00, b01, k0 + 128);
    __syncthreads();
    MFMA_STEP();
    p ^= 1;
    STAGE(a10, a11, a12, a13, b10, b11);
    LOADSET(a10, a11, a12, a13, b10, b11, k0 + 192);
    __syncthreads();
    MFMA_STEP();
    p ^= 1;
    k0 += 128;
  }
  if (k0 < ke) {           // odd tail chunk (last split: 37 chunks)
    STAGE(a00, a01, a02, a03, b00, b01);
    __syncthreads();
    MFMA_STEP();
    p ^= 1;
  }
#undef LOADSET
#undef STAGE
#undef MFMA_STEP

#pragma unroll
  for (int mi = 0; mi < 2; ++mi) {
    const int row0 = bm * 64 + wm * 32 + mi * 16 + l4 * 4;
#pragma unroll
    for (int ni = 0; ni < 2; ++ni) {
      const int cc = bn * 64 + wn * 32 + ni * 16 + l15;
#pragma unroll
      for (int r2 = 0; r2 < 4; ++r2) {
        const int row = row0 + r2;
        if (row < NN) outp[(long)row * HH1 + cc] = acc[mi][ni][r2];
      }
    }
  }
}

// ---------------- reduce 4 partials -> ht1 --------------
__global__ void k_red1(const float* __restrict__ P0, const float* __restrict__ P1,
    const float* __restrict__ P2, const float* __restrict__ P3,
    float* __restrict__ o) {
  const long i = (long)(blockIdx.x * 256 + threadIdx.x) * 4;
  f32x4 a = *(const f32x4*)(P0 + i);
  f32x4 b = *(const f32x4*)(P1 + i);
  f32x4 c = *(const f32x4*)(P2 + i);
  f32x4 d = *(const f32x4*)(P3 + i);
  *(f32x4*)(o + i) = (a + b) + (c + d);
}

// ---------------- aggregate layer 1 (+relu) ----------------
__global__ void k_agg1(const float* __restrict__ ht1, const int* __restrict__ rowst,
    const int* __restrict__ csrc, const float* __restrict__ cw,
    const float* __restrict__ invd, const float* __restrict__ b1,
    float* __restrict__ h) {
  const int node = blockIdx.x;
  const int j = threadIdx.x;
  const int s = rowst[node], e = rowst[node + 1];
  float acc = 0.f;
  for (int p = s; p < e; ++p)
    acc = fmaf(cw[p], ht1[(long)csrc[p] * HH1 + j], acc);
  float v = (acc + ht1[(long)node * HH1 + j]) * invd[node] + b1[j];
  h[(long)node * HH1 + j] = fmaxf(v, 0.f);
}

// ---------------- GEMM2: ht2 = h @ W2^T (f32 VALU) ----------------
__global__ __launch_bounds__(512) void k_gemm2(const float* __restrict__ h,
    const float* __restrict__ W2, float* __restrict__ ht2) {
  const int t = threadIdx.x;
  const int col = t & 127, rg = t >> 7;  // rg 0..3
  const long row0 = (long)blockIdx.x * 16 + rg * 4;
  const float* hp = h + row0 * HH1;
  const float* wp = W2 + col * HH1;
  float acc0 = 0.f, acc1 = 0.f, acc2 = 0.f, acc3 = 0.f;
  for (int k = 0; k < HH1; k += 4) {
    float4 wv = *(const float4*)(wp + k);
    float4 h0 = *(const float4*)(hp + k);
    float4 h1 = *(const float4*)(hp + HH1 + k);
    float4 h2 = *(const float4*)(hp + 2 * HH1 + k);
    float4 h3 = *(const float4*)(hp + 3 * HH1 + k);
    acc0 += h0.x * wv.x + h0.y * wv.y + h0.z * wv.z + h0.w * wv.w;
    acc1 += h1.x * wv.x + h1.y * wv.y + h1.z * wv.z + h1.w * wv.w;
    acc2 += h2.x * wv.x + h2.y * wv.y + h2.z * wv.z + h2.w * wv.w;
    acc3 += h3.x * wv.x + h3.y * wv.y + h3.z * wv.z + h3.w * wv.w;
  }
  ht2[row0 * HH2 + col] = acc0;
  ht2[(row0 + 1) * HH2 + col] = acc1;
  ht2[(row0 + 2) * HH2 + col] = acc2;
  ht2[(row0 + 3) * HH2 + col] = acc3;
}

// ---------------- aggregate layer 2 -> z (f32 out) + pre-swizzled bf16 ------
__global__ void k_agg2(const float* __restrict__ ht2, const int* __restrict__ rowst,
    const int* __restrict__ csrc, const float* __restrict__ cw,
    const float* __restrict__ invd, const float* __restrict__ b2,
    float* __restrict__ zout, short* __restrict__ zb) {
  const int node = blockIdx.x;
  const int j = threadIdx.x;
  const int s = rowst[node], e = rowst[node + 1];
  float acc = 0.f;
  for (int p = s; p < e; ++p)
    acc = fmaf(cw[p], ht2[(long)csrc[p] * HH2 + j], acc);
  float v = (acc + ht2[(long)node * HH2 + j]) * invd[node] + b2[j];
  zout[(long)node * HH2 + j] = v;
  const int slot = j >> 3, pos = j & 7;
  zb[node * HH2 + ((slot ^ (node & 15)) << 3) + pos] = f2bf(v);
}

// ---------------- adj = z @ z^T (bf16 MFMA, K=128, tile 128x128) ------------
__global__ __launch_bounds__(256) void k_adj(const short* __restrict__ zb,
                                             float* __restrict__ adj) {
  __shared__ short As[128 * 128];
  __shared__ short Bs[128 * 128];
  const int bmi = blockIdx.y, bni = blockIdx.x;
  const int t = threadIdx.x;
  const int lane = t & 63;
  const int wid = t >> 6;
  const int wm = wid >> 1, wn = wid & 1;
  const int l15 = lane & 15, l4 = lane >> 4;
  const int sr = t >> 4;   // 0..15
  const int ss = t & 15;
#pragma unroll
  for (int it = 0; it < 8; ++it) {
    const int r = it * 16 + sr;
    const long ga = (long)min(bmi * 128 + r, NN - 1) * HH2;
    const long gb = (long)min(bni * 128 + r, NN - 1) * HH2;
    *(short8*)((short*)As + r * 128 + ss * 8) = *(const short8*)(zb + ga + ss * 8);
    *(short8*)((short*)Bs + r * 128 + ss * 8) = *(const short8*)(zb + gb + ss * 8);
  }
  __syncthreads();
  f32x4 acc[4][4];
  const f32x4 zz = {0.f, 0.f, 0.f, 0.f};
#pragma unroll
  for (int mi = 0; mi < 4; ++mi)
#pragma unroll
    for (int ni = 0; ni < 4; ++ni) acc[mi][ni] = zz;
#pragma unroll
  for (int k4 = 0; k4 < 4; ++k4) {
    const int es = ((k4 * 4 + l4) ^ l15) * 8;
    short8 af[4], bf[4];
#pragma unroll
    for (int mi = 0; mi < 4; ++mi)
      af[mi] = *(const short8*)((short*)As + (wm * 64 + mi * 16 + l15) * 128 + es);
#pragma unroll
    for (int ni = 0; ni < 4; ++ni)
      bf[ni] = *(const short8*)((short*)Bs + (wn * 64 + ni * 16 + l15) * 128 + es);
#pragma unroll
    for (int mi = 0; mi < 4; ++mi)
#pragma unroll
      for (int ni = 0; ni < 4; ++ni)
        acc[mi][ni] = __builtin_amdgcn_mfma_f32_16x16x32_bf16(af[mi], bf[ni], acc[mi][ni], 0, 0, 0);
  }
#pragma unroll
  for (int mi = 0; mi < 4; ++mi) {
    const int row0 = bmi * 128 + wm * 64 + mi * 16 + l4 * 4;
#pragma unroll
    for (int ni = 0; ni < 4; ++ni) {
      const int cc = bni * 128 + wn * 64 + ni * 16 + l15;
      if (cc < NN) {
#pragma unroll
        for (int r = 0; r < 4; ++r) {
          const int row = row0 + r;
          if (row < NN) adj[(long)row * NN + cc] = acc[mi][ni][r];
        }
      }
    }
  }
}

// ---------------- launch ----------------
extern "C" void kernel_launch(void* const* d_in, const int* in_sizes, int n_in,
                              void* d_out, int out_size, void* d_ws, size_t ws_size,
                              hipStream_t stream) {
  (void)in_sizes; (void)n_in; (void)out_size; (void)ws_size;
  const float* feat = (const float*)d_in[0];
  const float* W1   = (const float*)d_in[1];
  const float* b1   = (const float*)d_in[2];
  const float* W2   = (const float*)d_in[3];
  const float* b2   = (const float*)d_in[4];
  const float* ew   = (const float*)d_in[5];
  const int*   srcv = (const int*)d_in[6];
  const int*   dstv = (const int*)d_in[7];

  float* zout = (float*)d_out;
  float* adj  = zout + (long)NN * HH2;

  // workspace layout
  float* ht1  = (float*)d_ws;                 // NN*HH1 f32 = partial 0; later ht2
  float* hbuf = ht1 + (long)NN * HH1;         // NN*HH1 f32 = partial 1; later h
  short* w1b  = (short*)(hbuf + (long)NN * HH1); // NN*HH1 bf16
  short* zb   = w1b + (long)NN * HH1;         // NN*HH2 bf16 (pre-swizzled)
  int*   degi = (int*)(zb + (long)NN * HH2);  // NN
  int*   rowst = degi + NN;                   // NN+1 (pad 16)
  int*   cursor = rowst + NN + 16;            // NN
  int*   csrc = cursor + NN;                  // EE
  float* cw   = (float*)(csrc + EE);          // EE
  float* invd = cw + EE;                      // NN
  float* P2   = invd + NN + 16;               // NN*HH1 f32 = partial 2
  float* P3   = P2 + (long)NN * HH1;          // NN*HH1 f32 = partial 3
  float* ht2  = ht1;                          // alias (ht1 dead after k_agg1)

  hipMemsetAsync(degi, 0, NN * sizeof(int), stream);
  k_count<<<(EE + 255) / 256, 256, 0, stream>>>(dstv, degi);
  k_scan<<<1, 1024, 0, stream>>>(degi, rowst, cursor, invd);
  k_fill<<<(EE + 255) / 256, 256, 0, stream>>>(srcv, dstv, ew, cursor, csrc, cw);
  k_w1bf<<<1250, 256, 0, stream>>>(W1, w1b);
  k_gemm1<<<640 * NSPLIT, 256, 0, stream>>>(feat, w1b, ht1, hbuf, P2, P3);
  k_red1<<<2500, 256, 0, stream>>>(ht1, hbuf, P2, P3, ht1);
  k_agg1<<<NN, 256, 0, stream>>>(ht1, rowst, csrc, cw, invd, b1, hbuf);
  k_gemm2<<<625, 512, 0, stream>>>(hbuf, W2, ht2);
  k_agg2<<<NN, 128, 0, stream>>>(ht2, rowst, csrc, cw, invd, b2, zout, zb);
  k_adj<<<dim3(79, 79), 256, 0, stream>>>(zb, adj);
}